// Round 4
// baseline (83.157 us; speedup 1.0000x reference)
//
#include <hip/hip_runtime.h>

#define NN 2048
#define NH 4
#define COLS 256   // NH*F_OUT

typedef __attribute__((ext_vector_type(8))) short short8;
typedef __attribute__((ext_vector_type(4))) float f32x4;
typedef __attribute__((ext_vector_type(4))) int i32x4;

__device__ __forceinline__ ushort f2bf(float x) {
  union { float f; unsigned u; } v; v.f = x;
  unsigned r = v.u + 0x7fffu + ((v.u >> 16) & 1u);
  return (ushort)(r >> 16);
}

// ---------------------------------------------------------------------------
// Kernel 1: h = X @ W (f32 accum), emit:
//   hT   : bf16, layout [bh][f][n]  (bh = b*4+head; internal scratch)
//   s_src/s_dst : f32 [bh][n]
// grid 512 x 256; thread owns output column c = tid (head = c>>6, f = c&63).
// ---------------------------------------------------------------------------
__global__ __launch_bounds__(256) void k1_prep(
    const float* __restrict__ nf, const float* __restrict__ W,
    const float* __restrict__ att, ushort* __restrict__ hT,
    float* __restrict__ s_src, float* __restrict__ s_dst)
{
  const int tid = threadIdx.x;
  const int head = tid >> 6, lane = tid & 63;   // lane == f for this column
  const int bid = blockIdx.x;

  float w[64];
  #pragma unroll
  for (int f = 0; f < 64; ++f) w[f] = W[f * COLS + tid];   // coalesced

  const float asrc = att[head * 128 + lane];        // a_src[head][f]
  const float adst = att[head * 128 + 64 + lane];   // a_dst[head][f]

  __shared__ float xs[512];   // 8 rows x 64 features

  #pragma unroll 1
  for (int g = 0; g < 2; ++g) {
    const int m0 = bid * 16 + g * 8;
    __syncthreads();
    xs[tid]       = nf[m0 * 64 + tid];
    xs[tid + 256] = nf[m0 * 64 + 256 + tid];
    __syncthreads();

    float hv[8];
    #pragma unroll
    for (int rr = 0; rr < 8; ++rr) {
      float acc = 0.f;
      #pragma unroll
      for (int f = 0; f < 64; ++f) acc = fmaf(xs[rr * 64 + f], w[f], acc);
      hv[rr] = acc;
      float vs = acc * asrc, vd = acc * adst;
      #pragma unroll
      for (int off = 32; off > 0; off >>= 1) {
        vs += __shfl_xor(vs, off);
        vd += __shfl_xor(vd, off);
      }
      if (lane == 0) {
        const int m = m0 + rr;
        const int b = m >> 11, n = m & (NN - 1);
        s_src[(b * NH + head) * NN + n] = vs;
        s_dst[(b * NH + head) * NN + n] = vd;
      }
    }

    // hT[bh][f=lane][n0..n0+7] — one aligned 16B store
    const int b = m0 >> 11, n0 = m0 & (NN - 1);
    unsigned pk[4];
    #pragma unroll
    for (int e = 0; e < 4; ++e)
      pk[e] = (unsigned)f2bf(hv[2 * e]) | ((unsigned)f2bf(hv[2 * e + 1]) << 16);
    uint4 vv; vv.x = pk[0]; vv.y = pk[1]; vv.z = pk[2]; vv.w = pk[3];
    *(uint4*)(hT + (((size_t)(b * NH + head) * 64 + lane) * NN) + n0) = vv;
  }
}

// ---------------------------------------------------------------------------
// Kernel 2: fused mask + leakyrelu + softmax + P@H via MFMA 16x16x32 bf16.
// grid = B*(N/32) = 256 blocks x 256 threads; wave = head, 32 i-rows/block.
// A-frag: lane l = P[i0+(l&15)][jc*32 + 8*(l>>4) + e]   (generated in-register)
// B-frag: lane l = h[jc*32 + 8*(l>>4) + e][f = t*16 + (l&15)]  (short8 from hT)
// D     : lane l reg r = out row i0 + s*16 + 4*(l>>4)+r, col t*16 + (l&15)
// OUTPUT IS FLOAT32 (reference dtype) — round-1..3 failures were bf16 writes
// into a float* buffer; all three kernels computed identical correct values.
// ---------------------------------------------------------------------------
__global__ __launch_bounds__(256) void k2_main(
    const int* __restrict__ adj, const ushort* __restrict__ hT,
    const float* __restrict__ s_src, const float* __restrict__ s_dst,
    float* __restrict__ out)
{
  const int tid = threadIdx.x;
  const int w   = tid >> 6;           // head
  const int l   = tid & 63;
  const int bid = blockIdx.x;
  const int b   = bid >> 6;
  const int i0  = (bid & 63) << 5;

  const int bh   = b * NH + w;
  const int r16  = l & 15;
  const int grp  = l >> 4;
  const int koff = grp << 3;

  const float ssl = s_src[bh * NN + i0 + r16];
  const float ssh = s_src[bh * NN + i0 + 16 + r16];

  const float*  sdp  = s_dst + bh * NN;
  const int*    adjl = adj + (size_t)(b * NN + i0 + r16) * NN;
  const int*    adjh = adjl + (size_t)16 * NN;
  const ushort* ht   = hT + ((size_t)bh * 64 + r16) * NN + koff;

  f32x4 acc[8];   // [s*4+t]
  #pragma unroll
  for (int q = 0; q < 8; ++q) acc[q] = (f32x4){0.f, 0.f, 0.f, 0.f};
  float dl = 0.f, dh = 0.f;

  #pragma unroll 1
  for (int jc = 0; jc < NN / 32; ++jc) {
    const int jb = jc * 32 + koff;
    const f32x4 sd0 = *(const f32x4*)(sdp + jb);
    const f32x4 sd1 = *(const f32x4*)(sdp + jb + 4);
    const i32x4 al0 = *(const i32x4*)(adjl + jb);
    const i32x4 al1 = *(const i32x4*)(adjl + jb + 4);
    const i32x4 ah0 = *(const i32x4*)(adjh + jb);
    const i32x4 ah1 = *(const i32x4*)(adjh + jb + 4);
    const short8 hb0 = *(const short8*)(ht + jc * 32);
    const short8 hb1 = *(const short8*)(ht + 16 * NN + jc * 32);
    const short8 hb2 = *(const short8*)(ht + 32 * NN + jc * 32);
    const short8 hb3 = *(const short8*)(ht + 48 * NN + jc * 32);

    short8 pal, pah;
    #pragma unroll
    for (int e = 0; e < 8; ++e) {
      const float sdv = (e < 4) ? sd0[e] : sd1[e - 4];
      const int   avl = (e < 4) ? al0[e] : al1[e - 4];
      const int   avh = (e < 4) ? ah0[e] : ah1[e - 4];
      float x = ssl + sdv;
      x = fmaxf(x, 0.2f * x);
      float p = __expf(x);
      p = avl ? p : 0.f;
      dl += p;
      pal[e] = (short)f2bf(p);
      float y = ssh + sdv;
      y = fmaxf(y, 0.2f * y);
      float q = __expf(y);
      q = avh ? q : 0.f;
      dh += q;
      pah[e] = (short)f2bf(q);
    }

    acc[0] = __builtin_amdgcn_mfma_f32_16x16x32_bf16(pal, hb0, acc[0], 0, 0, 0);
    acc[1] = __builtin_amdgcn_mfma_f32_16x16x32_bf16(pal, hb1, acc[1], 0, 0, 0);
    acc[2] = __builtin_amdgcn_mfma_f32_16x16x32_bf16(pal, hb2, acc[2], 0, 0, 0);
    acc[3] = __builtin_amdgcn_mfma_f32_16x16x32_bf16(pal, hb3, acc[3], 0, 0, 0);
    acc[4] = __builtin_amdgcn_mfma_f32_16x16x32_bf16(pah, hb0, acc[4], 0, 0, 0);
    acc[5] = __builtin_amdgcn_mfma_f32_16x16x32_bf16(pah, hb1, acc[5], 0, 0, 0);
    acc[6] = __builtin_amdgcn_mfma_f32_16x16x32_bf16(pah, hb2, acc[6], 0, 0, 0);
    acc[7] = __builtin_amdgcn_mfma_f32_16x16x32_bf16(pah, hb3, acc[7], 0, 0, 0);
  }

  // denominators: sum the 4 koff lane-groups (lanes l, l^16, l^32, l^48)
  dl += __shfl_xor(dl, 16); dl += __shfl_xor(dl, 32);
  dh += __shfl_xor(dh, 16); dh += __shfl_xor(dh, 32);

  __shared__ float dsm[NH][32];
  if (l < 16) { dsm[w][l] = dl; dsm[w][16 + l] = dh; }
  __syncthreads();

  float rden[2][4];
  #pragma unroll
  for (int s = 0; s < 2; ++s)
    #pragma unroll
    for (int r = 0; r < 4; ++r)
      rden[s][r] = 1.0f / dsm[w][s * 16 + grp * 4 + r];

  #pragma unroll
  for (int s = 0; s < 2; ++s) {
    #pragma unroll
    for (int t = 0; t < 4; ++t) {
      const f32x4 a = acc[s * 4 + t];
      #pragma unroll
      for (int r = 0; r < 4; ++r) {
        const int i = i0 + s * 16 + grp * 4 + r;
        const size_t oidx = ((size_t)(b * NN + i) * COLS) + w * 64 + t * 16 + r16;
        out[oidx] = a[r] * rden[s][r];   // f32 store — reference output dtype
      }
    }
  }
}

// ---------------------------------------------------------------------------
extern "C" void kernel_launch(void* const* d_in, const int* in_sizes, int n_in,
                              void* d_out, int out_size, void* d_ws, size_t ws_size,
                              hipStream_t stream) {
  const float* nf  = (const float*)d_in[0];
  const int*   adj = (const int*)d_in[1];
  const float* W   = (const float*)d_in[2];
  const float* att = (const float*)d_in[3];

  ushort* hT    = (ushort*)d_ws;                                  // 4 MB
  float*  s_src = (float*)((char*)d_ws + (size_t)16 * 64 * NN * 2);
  float*  s_dst = s_src + 16 * NN;

  hipLaunchKernelGGL(k1_prep, dim3(512), dim3(256), 0, stream,
                     nf, W, att, hT, s_src, s_dst);
  hipLaunchKernelGGL(k2_main, dim3(256), dim3(256), 0, stream,
                     adj, hT, s_src, s_dst, (float*)d_out);
}